// Round 9
// baseline (206.390 us; speedup 1.0000x reference)
//
#include <hip/hip_runtime.h>

// PointNet fused kernel for MI355X (gfx950) — round 9.
//
// Algebra: segment-MLP + cb are per-row constants -> cancel in the per-row
// min/max rescale. Only s1[m,n] = feat·cW[0:6] + relu(MLP3(feat))·cW[6:262]
// matters, then per-row rescale to [-1,1].
//
// Round-9: async weight staging. R4/R8 ran the W2/W3 stream (256 KB/block
// from L2, ~60 us/CU of transfer) serially against the MFMA chain (~70 us
// floor) -> 160 us. Now L2+L3 form one 16-step K-stream; each step stages
// the NEXT 16 KB ks-tile into an LDS ping-pong via global_load_lds (async
// DMA, linear dest) while computing the CURRENT step from LDS (4 A + 4 B
// ds_read_b128, conflict-free) -> 16 MFMA. One vmcnt(0)+barrier per step
// (2-phase). h1->h2 in-place epilogue sits between steps 7/8 with the t=8
// DMA already in flight. LDS 69 KB -> 2 blocks/CU.

typedef __attribute__((ext_vector_type(8))) short short8;   // 8 bf16
typedef __attribute__((ext_vector_type(4))) float f32x4;    // MFMA accum
typedef __attribute__((ext_vector_type(4))) unsigned int u32x4;

#define THREADS 256

#define LDS_AS(p) ((__attribute__((address_space(3))) unsigned int*)(p))
#define GLB_AS(p) ((const __attribute__((address_space(1))) unsigned int*)(p))

__device__ __forceinline__ unsigned short f2bf(float f) {
  union { float f; unsigned int u; } x; x.f = f;
  unsigned int r = x.u + 0x7fffu + ((x.u >> 16) & 1u);   // RNE
  return (unsigned short)(r >> 16);
}

__device__ __forceinline__ unsigned int cvt_pk_bf16(float lo, float hi) {
  unsigned int r;
  asm("v_cvt_pk_bf16_f32 %0, %1, %2" : "=v"(r) : "v"(lo), "v"(hi));
  return r;
}

// ---------------------------------------------------------------------------
// k0: pack weights into MFMA A-fragment order (unchanged):
//   idx(s,ct,hi,col,j) = (((s*16+ct)*4+hi)*16+col)*8 + j
//   k = s*32 + hi*8 + j (zero past Kreal), c = ct*16 + col
// Regions (ushort): W1 @0 (8192), W2 @8192 (65536), W3 @73728 (65536)
// ---------------------------------------------------------------------------
__global__ void pn_pack(const float* __restrict__ W1,
                        const float* __restrict__ W2,
                        const float* __restrict__ W3,
                        unsigned short* __restrict__ wp) {
  int e = blockIdx.x * 256 + threadIdx.x;           // 0 .. 139263
  const float* src; int Kreal, base, r;
  if (e < 8192)       { src = W1; Kreal = 6;   base = 0;     r = e; }
  else if (e < 73728) { src = W2; Kreal = 256; base = 8192;  r = e - 8192; }
  else                { src = W3; Kreal = 256; base = 73728; r = e - 73728; }
  int j   = r & 7;
  int col = (r >> 3) & 15;
  int hi  = (r >> 7) & 3;
  int ct  = (r >> 9) & 15;
  int s   = r >> 13;
  int k = s * 32 + hi * 8 + j;
  int c = ct * 16 + col;
  float v = (k < Kreal) ? src[k * 256 + c] : 0.0f;
  wp[base + r] = f2bf(v);
}

// ---------------------------------------------------------------------------
// k1 helpers. Per wave: 64 channels (cgrp=wave) x 64 points.
// ---------------------------------------------------------------------------

// async-stage one 16 KB ks-tile (8192 ushort) into LDS, linear layout.
// wave w handles rows {w, 4+w, 8+w, 12+w} of 16 x 1KB rows.
__device__ __forceinline__ void stage16k(const unsigned short* __restrict__ gsrc,
                                         unsigned short* lbase,
                                         int wave, int lane) {
#pragma unroll
  for (int r = 0; r < 4; ++r) {
    const unsigned short* g = gsrc + (((r * 4 + wave) * 64 + lane) << 3);
    unsigned short* l = lbase + (((r * 4 + wave) * 64) << 3);  // wave-uniform
    __builtin_amdgcn_global_load_lds(GLB_AS(g), LDS_AS(l), 16, 0, 0);
  }
}

// init acc with per-channel bias (broadcast over points)
__device__ __forceinline__ void acc_init(f32x4 (&acc)[4][4], const float* bv,
                                         int cgrp, int hi) {
#pragma unroll
  for (int cf = 0; cf < 4; ++cf) {
    f32x4 bi = *(const f32x4*)(bv + cgrp * 64 + cf * 16 + hi * 4);
#pragma unroll
    for (int pf = 0; pf < 4; ++pf) acc[cf][pf] = bi;
  }
}

// relu -> bf16 (cvt_pk) -> swizzled h buffer, b64 writes (bias already in acc)
__device__ __forceinline__ void epi_h(f32x4 (&acc)[4][4], unsigned short* dst,
                                      int cgrp, int l15, int hi) {
#pragma unroll
  for (int cf = 0; cf < 4; ++cf) {
    int c0 = cgrp * 64 + cf * 16 + hi * 4;
#pragma unroll
    for (int pf = 0; pf < 4; ++pf) {
      int p = pf * 16 + l15;
      f32x4 a = acc[cf][pf];
      unsigned int lo  = cvt_pk_bf16(fmaxf(a[0], 0.0f), fmaxf(a[1], 0.0f));
      unsigned int hi2 = cvt_pk_bf16(fmaxf(a[2], 0.0f), fmaxf(a[3], 0.0f));
      unsigned long long w = (unsigned long long)lo | ((unsigned long long)hi2 << 32);
      int byteoff = ((p * 256 + c0) * 2) ^ ((p & 7) << 4);
      *(unsigned long long*)((char*)dst + byteoff) = w;
    }
  }
}

// ---------------------------------------------------------------------------
// k1: one block = 64 points of one bbox row; 4 waves; ~69 KB LDS, 2 blk/CU.
// ---------------------------------------------------------------------------
__global__ __launch_bounds__(THREADS, 1) void pn_main(
    const float* __restrict__ feat,
    const unsigned short* __restrict__ wp,
    const float* __restrict__ b1,
    const float* __restrict__ b2,
    const float* __restrict__ b3,
    const float* __restrict__ cW,
    float* __restrict__ out) {
  __shared__ unsigned short hA[64 * 256];    // 32 KB swizzled h (in-place)
  __shared__ unsigned short wst[2][8192];    // 32 KB weight ks-tile ping-pong
  __shared__ unsigned short hF[64 * 8];      // 1 KB layer-1 B slice
  __shared__ float biasL[3 * 256];           // 3 KB
  __shared__ float whL[256];                 // 1 KB (cW[6..261])
  float* sPart = (float*)hF;                 // overlay: hF dead after L1

  const int tid  = threadIdx.x;
  const int lane = tid & 63;
  const int wave = tid >> 6;
  const int l15  = lane & 15;
  const int hi   = lane >> 4;
  const int cgrp = wave;         // channel group (64 of 256)

  const int blk = blockIdx.x;
  const int m   = blk >> 7;                  // 128 blocks per bbox row
  const int n0  = (blk & 127) << 6;
  const int g0  = m * 8192 + n0;

  // ---- kick off DMA for K-stream step 0 (W2 ks0) immediately
  stage16k(wp + 8192, wst[0], wave, lane);

  // ---- stage biases + classifier hidden weights
  biasL[tid]       = b1[tid & 255];
  biasL[256 + tid] = b2[tid & 255];
  biasL[512 + tid] = b3[tid & 255];
  whL[tid & 255]   = cW[6 + (tid & 255)];

  // ---- build hF (k0..7 slice) + fdot in register
  float fdot = 0.0f;
  if (tid < 64) {
    const float* fp = feat + (g0 + tid) * 6;
    float f0 = fp[0], f1 = fp[1], f2 = fp[2], f3 = fp[3], f4 = fp[4], f5 = fp[5];
    fdot = f0 * cW[0] + f1 * cW[1] + f2 * cW[2] + f3 * cW[3] + f4 * cW[4] + f5 * cW[5];
    u32x4 v;
    v[0] = cvt_pk_bf16(f0, f1);
    v[1] = cvt_pk_bf16(f2, f3);
    v[2] = cvt_pk_bf16(f4, f5);
    v[3] = 0;
    *(u32x4*)(hF + tid * 8) = v;
  }

  // ---- W1 fragments straight from L2 (tiny, once)
  short8 w1r[4];
#pragma unroll
  for (int cf = 0; cf < 4; ++cf)
    w1r[cf] = *(const short8*)(wp + ((((cgrp * 4 + cf) * 4 + hi) * 16 + l15) << 3));

  __syncthreads();   // hF/bias visible (DMA still in flight)

  f32x4 acc[4][4];
  const short8 zero8 = {0, 0, 0, 0, 0, 0, 0, 0};

  // ---- layer 1 (K padded to 32; only hi==0 k-slots nonzero)
  acc_init(acc, biasL + 0, cgrp, hi);
#pragma unroll
  for (int pf = 0; pf < 4; ++pf) {
    int p = pf * 16 + l15;
    short8 b = (hi == 0) ? *(const short8*)(hF + p * 8) : zero8;
#pragma unroll
    for (int cf = 0; cf < 4; ++cf)
      acc[cf][pf] = __builtin_amdgcn_mfma_f32_16x16x32_bf16(
          w1r[cf], b, acc[cf][pf], 0, 0, 0);
  }
  epi_h(acc, hA, cgrp, l15, hi);           // h1 -> hA
  acc_init(acc, biasL + 256, cgrp, hi);    // pre-init for L2

  asm volatile("s_waitcnt vmcnt(0)");      // step-0 tile staged
  __syncthreads();                         // hA + wst[0] visible

  // ---- unified 16-step K-stream: t<8 -> L2 (W2), t>=8 -> L3 (W3)
#pragma unroll 1
  for (int t = 0; t < 16; ++t) {
    if (t + 1 < 16) {
      const unsigned short* src = wp +
          ((t + 1 < 8) ? (8192 + (t + 1) * 8192) : (73728 + (t - 7) * 8192));
      stage16k(src, wst[(t + 1) & 1], wave, lane);
    }
    const unsigned short* wt = wst[t & 1];
    short8 afr[4], bfr[4];
#pragma unroll
    for (int cf = 0; cf < 4; ++cf)
      afr[cf] = *(const short8*)(wt + ((((cgrp * 4 + cf) * 4 + hi) * 16 + l15) << 3));
    int ksl = t & 7;
#pragma unroll
    for (int pf = 0; pf < 4; ++pf) {
      int p = pf * 16 + l15;
      int byteoff = ((p * 256 + ksl * 32 + hi * 8) * 2) ^ ((p & 7) << 4);
      bfr[pf] = *(const short8*)((const char*)hA + byteoff);
    }
#pragma unroll
    for (int cf = 0; cf < 4; ++cf)
#pragma unroll
      for (int pf = 0; pf < 4; ++pf)
        acc[cf][pf] = __builtin_amdgcn_mfma_f32_16x16x32_bf16(
            afr[cf], bfr[pf], acc[cf][pf], 0, 0, 0);

    if (t == 7) {
      __syncthreads();                     // all h1 reads complete
      epi_h(acc, hA, cgrp, l15, hi);       // h2 -> hA in place
      acc_init(acc, biasL + 512, cgrp, hi);
    }
    asm volatile("s_waitcnt vmcnt(0)");    // next tile staged
    __syncthreads();                       // buffers consistent block-wide
  }

  // ---- classifier dot + per-point reduce
  float part[4] = {0.f, 0.f, 0.f, 0.f};
#pragma unroll
  for (int cf = 0; cf < 4; ++cf) {
    int c0 = cgrp * 64 + cf * 16 + hi * 4;
#pragma unroll
    for (int r = 0; r < 4; ++r) {
      float wv = whL[c0 + r];
#pragma unroll
      for (int pf = 0; pf < 4; ++pf)
        part[pf] += fmaxf(acc[cf][pf][r], 0.0f) * wv;
    }
  }
#pragma unroll
  for (int off = 16; off < 64; off <<= 1)
#pragma unroll
    for (int pf = 0; pf < 4; ++pf)
      part[pf] += __shfl_xor(part[pf], off);
  if (hi == 0) {
#pragma unroll
    for (int pf = 0; pf < 4; ++pf)
      sPart[cgrp * 64 + pf * 16 + l15] = part[pf];
  }
  __syncthreads();

  if (tid < 64) {
    float s = sPart[tid] + sPart[64 + tid] + sPart[128 + tid] + sPart[192 + tid]
            + fdot;
    out[g0 + tid] = s;   // raw s1; rescaled by pn_finalize
  }
}

// ---------------------------------------------------------------------------
// k2: per-bbox min/max rescale to [-1,1], in place.
// ---------------------------------------------------------------------------
__global__ void pn_finalize(float* __restrict__ out) {
  __shared__ float smn[4], smx[4];
  int mrow = blockIdx.x;
  float* row = out + mrow * 8192;
  float v[32];
  float mn = 1e30f, mx = -1e30f;
#pragma unroll
  for (int i = 0; i < 32; ++i) {
    v[i] = row[threadIdx.x + i * 256];
    mn = fminf(mn, v[i]);
    mx = fmaxf(mx, v[i]);
  }
#pragma unroll
  for (int off = 1; off < 64; off <<= 1) {
    mn = fminf(mn, __shfl_xor(mn, off));
    mx = fmaxf(mx, __shfl_xor(mx, off));
  }
  int w = threadIdx.x >> 6;
  if ((threadIdx.x & 63) == 0) { smn[w] = mn; smx[w] = mx; }
  __syncthreads();
  mn = fminf(fminf(smn[0], smn[1]), fminf(smn[2], smn[3]));
  mx = fmaxf(fmaxf(smx[0], smx[1]), fmaxf(smx[2], smx[3]));
  float sc = 2.0f / (mx - mn);
#pragma unroll
  for (int i = 0; i < 32; ++i)
    row[threadIdx.x + i * 256] = (v[i] - mn) * sc - 1.0f;
}

// ---------------------------------------------------------------------------
extern "C" void kernel_launch(void* const* d_in, const int* in_sizes, int n_in,
                              void* d_out, int out_size, void* d_ws, size_t ws_size,
                              hipStream_t stream) {
  const float* feat = (const float*)d_in[0];
  const float* eW1  = (const float*)d_in[1];
  const float* eb1  = (const float*)d_in[2];
  const float* eW2  = (const float*)d_in[3];
  const float* eb2  = (const float*)d_in[4];
  const float* eW3  = (const float*)d_in[5];
  const float* eb3  = (const float*)d_in[6];
  // sW*/sb* (7..12) and cb (14) cancel in the per-row rescale -- unused.
  const float* cW   = (const float*)d_in[13];
  float* out = (float*)d_out;
  unsigned short* wpack = (unsigned short*)d_ws;   // 278,528 B of ws

  pn_pack<<<544, 256, 0, stream>>>(eW1, eW2, eW3, wpack);
  pn_main<<<8192, THREADS, 0, stream>>>(feat, wpack, eb1, eb2, eb3, cW, out);
  pn_finalize<<<64, 256, 0, stream>>>(out);
}

// Round 10
// 146.047 us; speedup vs baseline: 1.4132x; 1.4132x over previous
//
#include <hip/hip_runtime.h>

// PointNet fused kernel for MI355X (gfx950) — round 10.
//
// Algebra: segment-MLP + cb are per-row constants -> cancel in the per-row
// min/max rescale. Only s1[m,n] = feat·cW[0:6] + relu(MLP3(feat))·cW[6:262]
// matters, then per-row rescale to [-1,1].
//
// Round-10:
//  (1) PACKED-FRAGMENT h layout. The old row-major [pt][256] h buffer gave
//      8-way bank conflicts on every B-fragment ds_read_b128 (12.58M conflict
//      cycles/dispatch, constant across rounds 1-9). hP[ks][pfg][lane][8] makes
//      the gemm B-read 'base + lane*16' = 1 KB linear per wave (conflict-free);
//      a row-XOR (byte ^= ((byte>>7)&7)<<4, same on write+read) also makes the
//      epilogue b64 writes conflict-free.
//  (2) 128-pt blocks, 512 thr (4 cgrp x 2 pgrp waves): halves the L2 weight
//      stream (1.05 GB/dispatch); pgrp-duplicate A-loads are L1 hits.
//      LDS ~70 KB -> 2 blocks/CU at ~112 VGPR.

typedef __attribute__((ext_vector_type(8))) short short8;   // 8 bf16
typedef __attribute__((ext_vector_type(4))) float f32x4;    // MFMA accum
typedef __attribute__((ext_vector_type(4))) unsigned int u32x4;

#define THREADS 512

__device__ __forceinline__ unsigned short f2bf(float f) {
  union { float f; unsigned int u; } x; x.f = f;
  unsigned int r = x.u + 0x7fffu + ((x.u >> 16) & 1u);   // RNE
  return (unsigned short)(r >> 16);
}

__device__ __forceinline__ unsigned int cvt_pk_bf16(float lo, float hi) {
  unsigned int r;
  asm("v_cvt_pk_bf16_f32 %0, %1, %2" : "=v"(r) : "v"(lo), "v"(hi));
  return r;
}

// ---------------------------------------------------------------------------
// k0: pack weights into MFMA A-fragment order (unchanged):
//   idx(s,ct,hi,col,j) = (((s*16+ct)*4+hi)*16+col)*8 + j
//   k = s*32 + hi*8 + j (zero past Kreal), c = ct*16 + col
// Regions (ushort): W1 @0 (8192), W2 @8192 (65536), W3 @73728 (65536)
// ---------------------------------------------------------------------------
__global__ void pn_pack(const float* __restrict__ W1,
                        const float* __restrict__ W2,
                        const float* __restrict__ W3,
                        unsigned short* __restrict__ wp) {
  int e = blockIdx.x * 256 + threadIdx.x;           // 0 .. 139263
  const float* src; int Kreal, base, r;
  if (e < 8192)       { src = W1; Kreal = 6;   base = 0;     r = e; }
  else if (e < 73728) { src = W2; Kreal = 256; base = 8192;  r = e - 8192; }
  else                { src = W3; Kreal = 256; base = 73728; r = e - 73728; }
  int j   = r & 7;
  int col = (r >> 3) & 15;
  int hi  = (r >> 7) & 3;
  int ct  = (r >> 9) & 15;
  int s   = r >> 13;
  int k = s * 32 + hi * 8 + j;
  int c = ct * 16 + col;
  float v = (k < Kreal) ? src[k * 256 + c] : 0.0f;
  wp[base + r] = f2bf(v);
}

// ---------------------------------------------------------------------------
// k1 helpers. Per wave: 64 channels (cgrp) x 64 points (pgrp half of 128).
// hP packed layout: fragment (ks,pfg) at byte (ks*8+pfg)*1024, lane l at
// +l*16, holding h[pt=pfg*16+(l&15)][ch=ks*32+(l>>4)*8 .. +8].
// Row-XOR applied to all hP accesses: byte ^= ((byte>>7)&7)<<4.
// ---------------------------------------------------------------------------
__device__ __forceinline__ int hswz(int byteoff) {
  return byteoff ^ (((byteoff >> 7) & 7) << 4);
}

__device__ __forceinline__ void gemm256p(const unsigned short* __restrict__ wpL,
                                         const unsigned short* hP,
                                         int cgrp, int pgrp, int lane,
                                         int l15, int hi,
                                         f32x4 (&acc)[4][4]) {
#pragma unroll
  for (int ks = 0; ks < 8; ++ks) {
    short8 afr[4], bfr[4];
#pragma unroll
    for (int cf = 0; cf < 4; ++cf)                  // A from L2 (linear 1KB/wave)
      afr[cf] = *(const short8*)(wpL +
                 (((((ks * 16 + cgrp * 4 + cf) * 4) + hi) * 16 + l15) << 3));
#pragma unroll
    for (int pf = 0; pf < 4; ++pf) {                // B from LDS (linear 1KB/wave)
      int byteoff = ((ks * 8 + (pgrp * 4 + pf)) * 64 + lane) * 16;
      bfr[pf] = *(const short8*)((const char*)hP + hswz(byteoff));
    }
#pragma unroll
    for (int cf = 0; cf < 4; ++cf)
#pragma unroll
      for (int pf = 0; pf < 4; ++pf)
        acc[cf][pf] = __builtin_amdgcn_mfma_f32_16x16x32_bf16(
            afr[cf], bfr[pf], acc[cf][pf], 0, 0, 0);
  }
}

// init acc with per-channel bias (broadcast over points)
__device__ __forceinline__ void acc_init(f32x4 (&acc)[4][4], const float* bv,
                                         int cgrp, int hi) {
#pragma unroll
  for (int cf = 0; cf < 4; ++cf) {
    f32x4 bi = *(const f32x4*)(bv + cgrp * 64 + cf * 16 + hi * 4);
#pragma unroll
    for (int pf = 0; pf < 4; ++pf) acc[cf][pf] = bi;
  }
}

// relu -> bf16 -> packed hP (conflict-free b64 writes via row-XOR)
__device__ __forceinline__ void epi_hp(f32x4 (&acc)[4][4], unsigned short* hP,
                                       int cgrp, int pgrp, int l15, int hi) {
#pragma unroll
  for (int cf = 0; cf < 4; ++cf) {
    int ks2 = cgrp * 2 + (cf >> 1);
    int chi = (cf & 1) * 2 + (hi >> 1);
    int j0  = (hi & 1) * 4;
#pragma unroll
    for (int pf = 0; pf < 4; ++pf) {
      f32x4 a = acc[cf][pf];
      unsigned int lo  = cvt_pk_bf16(fmaxf(a[0], 0.0f), fmaxf(a[1], 0.0f));
      unsigned int hi2 = cvt_pk_bf16(fmaxf(a[2], 0.0f), fmaxf(a[3], 0.0f));
      unsigned long long w = (unsigned long long)lo | ((unsigned long long)hi2 << 32);
      int byteoff = (((ks2 * 8 + (pgrp * 4 + pf)) * 64 + chi * 16 + l15) * 16)
                  + j0 * 2;
      *(unsigned long long*)((char*)hP + hswz(byteoff)) = w;
    }
  }
}

// ---------------------------------------------------------------------------
// k1: one block = 128 points of one bbox row; 8 waves (4 cgrp x 2 pgrp);
// ~70 KB LDS -> 2 blocks/CU.
// ---------------------------------------------------------------------------
__global__ __launch_bounds__(THREADS, 1) void pn_main(
    const float* __restrict__ feat,
    const unsigned short* __restrict__ wp,
    const float* __restrict__ b1,
    const float* __restrict__ b2,
    const float* __restrict__ b3,
    const float* __restrict__ cW,
    float* __restrict__ out) {
  __shared__ unsigned short hP[64 * 1024 / 2];   // 64 KB packed h (in-place)
  __shared__ unsigned short hF[128 * 8];         // 2 KB layer-1 B slice
  __shared__ float biasL[3 * 256];               // 3 KB
  __shared__ float whL[256];                     // 1 KB (cW[6..261])
  float* sPart = (float*)hF;                     // overlay: hF dead after L1

  const int tid  = threadIdx.x;
  const int lane = tid & 63;
  const int wave = tid >> 6;
  const int l15  = lane & 15;
  const int hi   = lane >> 4;
  const int cgrp = wave & 3;     // channel group (64 of 256)
  const int pgrp = wave >> 2;    // point group (64 of 128)

  const int blk = blockIdx.x;
  const int m   = blk >> 6;                  // 64 blocks per bbox row
  const int n0  = (blk & 63) << 7;
  const int g0  = m * 8192 + n0;

  // ---- stage biases + classifier hidden weights
  if (tid < 256) {
    biasL[tid]       = b1[tid];
    biasL[256 + tid] = b2[tid];
    biasL[512 + tid] = b3[tid];
    whL[tid]         = cW[6 + tid];
  }

  // ---- build hF (k0..7 slice, 2 zeros) + fdot in register
  float fdot = 0.0f;
  if (tid < 128) {
    const float* fp = feat + (size_t)(g0 + tid) * 6;
    float f0 = fp[0], f1 = fp[1], f2 = fp[2], f3 = fp[3], f4 = fp[4], f5 = fp[5];
    fdot = f0 * cW[0] + f1 * cW[1] + f2 * cW[2] + f3 * cW[3] + f4 * cW[4] + f5 * cW[5];
    u32x4 v;
    v[0] = cvt_pk_bf16(f0, f1);
    v[1] = cvt_pk_bf16(f2, f3);
    v[2] = cvt_pk_bf16(f4, f5);
    v[3] = 0;
    *(u32x4*)(hF + tid * 8) = v;
  }
  __syncthreads();

  f32x4 acc[4][4];
  const short8 zero8 = {0, 0, 0, 0, 0, 0, 0, 0};

  // ---- layer 1 (K padded to 32; only hi==0 k-slots are nonzero)
  acc_init(acc, biasL + 0, cgrp, hi);
  {
    short8 afr[4], bfr[4];
#pragma unroll
    for (int cf = 0; cf < 4; ++cf)
      afr[cf] = *(const short8*)(wp + ((((cgrp * 4 + cf) * 4 + hi) * 16 + l15) << 3));
#pragma unroll
    for (int pf = 0; pf < 4; ++pf) {
      int p = pgrp * 64 + pf * 16 + l15;
      bfr[pf] = (hi == 0) ? *(const short8*)(hF + p * 8) : zero8;
    }
#pragma unroll
    for (int cf = 0; cf < 4; ++cf)
#pragma unroll
      for (int pf = 0; pf < 4; ++pf)
        acc[cf][pf] = __builtin_amdgcn_mfma_f32_16x16x32_bf16(
            afr[cf], bfr[pf], acc[cf][pf], 0, 0, 0);
  }
  epi_hp(acc, hP, cgrp, pgrp, l15, hi);      // h1 -> hP
  __syncthreads();

  // ---- layer 2 (reads hP=h1, writes hP=h2 in place after a barrier)
  acc_init(acc, biasL + 256, cgrp, hi);
  gemm256p(wp + 8192, hP, cgrp, pgrp, lane, l15, hi, acc);
  __syncthreads();                           // all h1 reads complete
  epi_hp(acc, hP, cgrp, pgrp, l15, hi);      // h2 -> hP
  __syncthreads();                           // h2 visible

  // ---- layer 3 + classifier dot
  acc_init(acc, biasL + 512, cgrp, hi);
  gemm256p(wp + 73728, hP, cgrp, pgrp, lane, l15, hi, acc);

  float part[4] = {0.f, 0.f, 0.f, 0.f};
#pragma unroll
  for (int cf = 0; cf < 4; ++cf) {
    int c0 = cgrp * 64 + cf * 16 + hi * 4;
#pragma unroll
    for (int r = 0; r < 4; ++r) {
      float wv = whL[c0 + r];
#pragma unroll
      for (int pf = 0; pf < 4; ++pf)
        part[pf] += fmaxf(acc[cf][pf][r], 0.0f) * wv;
    }
  }
  // reduce across hi groups (same point, different channels)
#pragma unroll
  for (int off = 16; off < 64; off <<= 1)
#pragma unroll
    for (int pf = 0; pf < 4; ++pf)
      part[pf] += __shfl_xor(part[pf], off);
  if (hi == 0) {
#pragma unroll
    for (int pf = 0; pf < 4; ++pf)
      sPart[cgrp * 128 + pgrp * 64 + pf * 16 + l15] = part[pf];
  }
  __syncthreads();

  if (tid < 128) {
    float s = sPart[tid] + sPart[128 + tid] + sPart[256 + tid] + sPart[384 + tid]
            + fdot;
    out[g0 + tid] = s;   // raw s1; rescaled by pn_finalize
  }
}

// ---------------------------------------------------------------------------
// k2: per-bbox min/max rescale to [-1,1], in place.
// ---------------------------------------------------------------------------
__global__ void pn_finalize(float* __restrict__ out) {
  __shared__ float smn[4], smx[4];
  int mrow = blockIdx.x;
  float* row = out + mrow * 8192;
  float v[32];
  float mn = 1e30f, mx = -1e30f;
#pragma unroll
  for (int i = 0; i < 32; ++i) {
    v[i] = row[threadIdx.x + i * 256];
    mn = fminf(mn, v[i]);
    mx = fmaxf(mx, v[i]);
  }
#pragma unroll
  for (int off = 1; off < 64; off <<= 1) {
    mn = fminf(mn, __shfl_xor(mn, off));
    mx = fmaxf(mx, __shfl_xor(mx, off));
  }
  int w = threadIdx.x >> 6;
  if ((threadIdx.x & 63) == 0) { smn[w] = mn; smx[w] = mx; }
  __syncthreads();
  mn = fminf(fminf(smn[0], smn[1]), fminf(smn[2], smn[3]));
  mx = fmaxf(fmaxf(smx[0], smx[1]), fmaxf(smx[2], smx[3]));
  float sc = 2.0f / (mx - mn);
#pragma unroll
  for (int i = 0; i < 32; ++i)
    row[threadIdx.x + i * 256] = (v[i] - mn) * sc - 1.0f;
}

// ---------------------------------------------------------------------------
extern "C" void kernel_launch(void* const* d_in, const int* in_sizes, int n_in,
                              void* d_out, int out_size, void* d_ws, size_t ws_size,
                              hipStream_t stream) {
  const float* feat = (const float*)d_in[0];
  const float* eW1  = (const float*)d_in[1];
  const float* eb1  = (const float*)d_in[2];
  const float* eW2  = (const float*)d_in[3];
  const float* eb2  = (const float*)d_in[4];
  const float* eW3  = (const float*)d_in[5];
  const float* eb3  = (const float*)d_in[6];
  // sW*/sb* (7..12) and cb (14) cancel in the per-row rescale -- unused.
  const float* cW   = (const float*)d_in[13];
  float* out = (float*)d_out;
  unsigned short* wpack = (unsigned short*)d_ws;   // 278,528 B of ws

  pn_pack<<<544, 256, 0, stream>>>(eW1, eW2, eW3, wpack);
  pn_main<<<4096, THREADS, 0, stream>>>(feat, wpack, eb1, eb2, eb3, cW, out);
  pn_finalize<<<64, 256, 0, stream>>>(out);
}